// Round 12
// baseline (235.998 us; speedup 1.0000x reference)
//
#include <hip/hip_runtime.h>
#include <hip/hip_bf16.h>

#define NNODE 100000
#define NEDGE 1600000
#define NBLK_SCAN 98     // ceil(100000/1024)
#define KPH_BLOCKS 1564  // covers 100096 nodes (64/block) and 400384 int4 edges
#define QINT4 100000     // int4s per histogram part (4 parts x 400k edges)
#define FLAGBIT 0x80000000u

static __device__ __forceinline__ uint32_t pack_bf16(float a, float b) {
    __hip_bfloat162 t = __float22bfloat162_rn(make_float2(a, b));
    return *(uint32_t*)&t;
}

// ---------------- K1: 4-way split hist atomics + register-only proj, fused ----------------
__global__ __launch_bounds__(256) void k_proj_hist(
        const float* __restrict__ hin, const float* __restrict__ Wfc,
        const float* __restrict__ attn_l, const float* __restrict__ attn_r,
        uint32_t* __restrict__ feat, float* __restrict__ el, float* __restrict__ er,
        const int* __restrict__ dst, int* __restrict__ cnt, int* __restrict__ pos) {
    int tid = threadIdx.x;
    // ---- hist: one int4 per thread, atomics to this quarter's sub-histogram ----
    int ei = blockIdx.x * 256 + tid;
    bool have = ei < NEDGE / 4;
    int4 d, p;
    int* cntp = nullptr;
    if (have) {
        unsigned part = (unsigned)ei / (unsigned)QINT4;   // 0..3
        cntp = cnt + part * NNODE;
        d = ((const int4*)dst)[ei];
        p.x = atomicAdd(&cntp[d.x], 1);
        p.y = atomicAdd(&cntp[d.y], 1);
        p.z = atomicAdd(&cntp[d.z], 1);
        p.w = atomicAdd(&cntp[d.w], 1);
    }
    // ---- proj: 16 nodes per wave, lane owns 2 cols, W pair in regs ----
    int l = tid & 63;
    int w = tid >> 6;
    int nbase = blockIdx.x * 64 + w * 16;
    int c0 = l * 2;
    float2 wreg[32];
#pragma unroll
    for (int k = 0; k < 32; k++)
        wreg[k] = *(const float2*)&Wfc[k * 128 + c0];
    float al0 = attn_l[c0], al1 = attn_l[c0 + 1];
    float ar0 = attn_r[c0], ar1 = attn_r[c0 + 1];
#pragma unroll 4
    for (int i = 0; i < 16; i++) {
        int n = nbase + i;
        if (n >= NNODE) break;           // wave-uniform
        float4 hv[8];
#pragma unroll
        for (int j = 0; j < 8; j++)
            hv[j] = *(const float4*)&hin[n * 32 + j * 4];   // broadcast load
        float a0 = 0.f, a1 = 0.f;
#pragma unroll
        for (int j = 0; j < 8; j++) {
            a0 = fmaf(hv[j].x, wreg[j * 4 + 0].x, a0); a1 = fmaf(hv[j].x, wreg[j * 4 + 0].y, a1);
            a0 = fmaf(hv[j].y, wreg[j * 4 + 1].x, a0); a1 = fmaf(hv[j].y, wreg[j * 4 + 1].y, a1);
            a0 = fmaf(hv[j].z, wreg[j * 4 + 2].x, a0); a1 = fmaf(hv[j].z, wreg[j * 4 + 2].y, a1);
            a0 = fmaf(hv[j].w, wreg[j * 4 + 3].x, a0); a1 = fmaf(hv[j].w, wreg[j * 4 + 3].y, a1);
        }
        float ep = a0 * al0 + a1 * al1;
        float rp = a0 * ar0 + a1 * ar1;
#pragma unroll
        for (int m = 8; m; m >>= 1) {
            ep += __shfl_xor(ep, m);
            rp += __shfl_xor(rp, m);
        }
        if ((l & 15) == 0) {
            el[n * 4 + (l >> 4)] = ep;
            er[n * 4 + (l >> 4)] = rp;
        }
        feat[(size_t)n * 64 + l] = pack_bf16(a0, a1);       // coalesced u32
    }
    // ---- pos (within-part rank) write: waits on atomic returns (hidden behind proj) ----
    if (have) ((int4*)pos)[ei] = p;
}

// ---------------- single-kernel scan: cnt4 -> offa + per-part bases pb[4][N] ----------------
__global__ __launch_bounds__(256) void k_scan(
        const int* __restrict__ cnt, unsigned* __restrict__ word,
        int* __restrict__ offa, int* __restrict__ pb) {
    __shared__ int s[256];
    __shared__ int sBase;
    int t = threadIdx.x;
    int b = blockIdx.x;
    int base = b * 1024 + t * 4;
    int vA[4], vB[4], vC[4], v[4];
#pragma unroll
    for (int i = 0; i < 4; i++) {
        int n = base + i;
        if (n < NNODE) {
            int a = cnt[n], bb = cnt[NNODE + n], c = cnt[2 * NNODE + n], dd = cnt[3 * NNODE + n];
            vA[i] = a; vB[i] = bb; vC[i] = c;
            v[i] = a + bb + c + dd;
        } else { vA[i] = vB[i] = vC[i] = 0; v[i] = 0; }
    }
    int sum = v[0] + v[1] + v[2] + v[3];
    s[t] = sum;
    __syncthreads();
    for (int d = 1; d < 256; d <<= 1) {
        int x = (t >= d) ? s[t - d] : 0;
        __syncthreads();
        s[t] += x;
        __syncthreads();
    }
    int excl = s[t] - sum;
    if (t == 255)
        __hip_atomic_store(&word[b], (unsigned)s[255] | FLAGBIT,
                           __ATOMIC_RELEASE, __HIP_MEMORY_SCOPE_AGENT);
    if (t < 64) {
        unsigned acc = 0;
        for (int i = t; i < b; i += 64) {
            unsigned wv;
            do {
                wv = __hip_atomic_load(&word[i], __ATOMIC_ACQUIRE, __HIP_MEMORY_SCOPE_AGENT);
            } while (!(wv & FLAGBIT));
            acc += wv & ~FLAGBIT;
        }
#pragma unroll
        for (int o = 32; o; o >>= 1) acc += __shfl_down(acc, o);
        if (t == 0) sBase = (int)acc;
    }
    __syncthreads();
    int o0 = sBase + excl;
#pragma unroll
    for (int i = 0; i < 4; i++) {
        int n = base + i;
        if (n < NNODE) {
            offa[n] = o0;
            pb[n] = o0;
            pb[NNODE + n] = o0 + vA[i];
            pb[2 * NNODE + n] = o0 + vA[i] + vB[i];
            pb[3 * NNODE + n] = o0 + vA[i] + vB[i] + vC[i];
            o0 += v[i];
        }
    }
    if (b == NBLK_SCAN - 1 && t == 255) offa[NNODE] = NEDGE;
}

// ---------------- scatter: atomic-free, part-base + within-part rank ----------------
__global__ __launch_bounds__(256) void k_scatter(const int* __restrict__ src,
                                                 const int* __restrict__ dst,
                                                 const int* __restrict__ pos,
                                                 const int* __restrict__ pb,
                                                 int* __restrict__ ssrc) {
    int i = blockIdx.x * 256 + threadIdx.x;
    if (i >= NEDGE / 4) return;
    unsigned part = (unsigned)i / (unsigned)QINT4;
    const int* pbp = pb + part * NNODE;
    int4 s = ((const int4*)src)[i];
    int4 d = ((const int4*)dst)[i];
    int4 p = ((const int4*)pos)[i];
    int o0 = pbp[d.x];
    int o1 = pbp[d.y];
    int o2 = pbp[d.z];
    int o3 = pbp[d.w];
    ssrc[o0 + p.x] = s.x;
    ssrc[o1 + p.y] = s.y;
    ssrc[o2 + p.z] = s.z;
    ssrc[o3 + p.w] = s.w;
}

// ---------------- K2': wave-per-node gather + softmax -> packed bf16 sv (no epilogue) ----
#define NPB 4
__global__ __launch_bounds__(256) void k_gather(
        const int* __restrict__ off, const int* __restrict__ ssrc,
        const float* __restrict__ el, const float* __restrict__ er,
        const uint32_t* __restrict__ feat, const float* __restrict__ bias_gat,
        uint32_t* __restrict__ svb) {
    __shared__ int sS[NPB][64];                         // 1 KB
    __shared__ __align__(16) float sE[NPB][64][4];      // 4 KB
    int tid = threadIdx.x;
    int w = tid >> 6;
    int l = tid & 63;
    int n = blockIdx.x * NPB + w;   // grid exact: 25000*4 = 100000
    int c0 = l * 2;
    int hh = l >> 4;
    float2 acc = make_float2(0.f, 0.f);
    float den = 0.f;
    int beg = off[n], end = off[n + 1];
    float4 erv = *(const float4*)&er[n * 4];

    for (int base = beg; base < end; base += 64) {
        int cnt = end - base; if (cnt > 64) cnt = 64;
        // phase A: pad to 8-multiple with zero weights (s=0 row is valid memory)
        int s = 0;
        float4 e4 = make_float4(0.f, 0.f, 0.f, 0.f);
        if (l < cnt) {
            s = ssrc[base + l];
            float4 ev = *(const float4*)&el[s * 4];
            e4.x = ev.x + erv.x; e4.x = e4.x > 0.f ? e4.x : 0.2f * e4.x; e4.x = __expf(e4.x);
            e4.y = ev.y + erv.y; e4.y = e4.y > 0.f ? e4.y : 0.2f * e4.y; e4.y = __expf(e4.y);
            e4.z = ev.z + erv.z; e4.z = e4.z > 0.f ? e4.z : 0.2f * e4.z; e4.z = __expf(e4.z);
            e4.w = ev.w + erv.w; e4.w = e4.w > 0.f ? e4.w : 0.2f * e4.w; e4.w = __expf(e4.w);
        }
        sS[w][l] = s;
        *(float4*)&sE[w][l][0] = e4;
        __builtin_amdgcn_wave_barrier();
        // phase B: unconditional 8-deep groups (padding contributes exactly 0)
        int rounds = (cnt + 7) >> 3;
        for (int r = 0; r < rounds; r++) {
            int e = r * 8;
            int ss[8]; float xx[8]; uint32_t uu[8];
#pragma unroll
            for (int q = 0; q < 8; q++) {
                ss[q] = sS[w][e + q];
                xx[q] = sE[w][e + q][hh];
            }
#pragma unroll
            for (int q = 0; q < 8; q++)
                uu[q] = feat[(uint32_t)ss[q] * 64u + (uint32_t)l];
#pragma unroll
            for (int q = 0; q < 8; q++) {
                den += xx[q];
                acc.x = fmaf(xx[q], __uint_as_float(uu[q] << 16), acc.x);
                acc.y = fmaf(xx[q], __uint_as_float(uu[q] & 0xffff0000u), acc.y);
            }
        }
        __builtin_amdgcn_wave_barrier();
    }
    float inv = 1.f / fmaxf(den, 1e-9f);
    float a0 = acc.x * inv + bias_gat[c0];
    float a1 = acc.y * inv + bias_gat[c0 + 1];
    svb[(size_t)n * 64 + l] = pack_bf16(a0, a1);   // coalesced
}

// ---------------- K3: out = h + ELU(sv @ Wout + b_out), sv bf16-packed ----------------
#define ONPB 32   // nodes per block; grid 3125 exact
__global__ __launch_bounds__(256) void k_out(
        const uint32_t* __restrict__ svb, const float* __restrict__ Wout,
        const float* __restrict__ b_out, const float* __restrict__ hin,
        float* __restrict__ out) {
    __shared__ float sW[128 * 32];        // 16 KB
    __shared__ uint32_t sV[ONPB * 64];    // 8 KB
    int tid = threadIdx.x;
    for (int i = tid * 4; i < 4096; i += 1024)
        *(float4*)&sW[i] = *(const float4*)&Wout[i];
    for (int i = tid * 8; i < ONPB * 64; i += 2048) {
        *(uint4*)&sV[i]     = *(const uint4*)&svb[(size_t)blockIdx.x * ONPB * 64 + i];
        *(uint4*)&sV[i + 4] = *(const uint4*)&svb[(size_t)blockIdx.x * ONPB * 64 + i + 4];
    }
    __syncthreads();
    int j = tid & 31, ng = tid >> 5;      // 8 groups of 32 cols
    float bj = b_out[j];
#pragma unroll
    for (int s = 0; s < 4; s++) {
        int nl = ng * 4 + s;
        int n = blockIdx.x * ONPB + nl;
        float p = bj;
        const uint32_t* vv = &sV[nl * 64];
#pragma unroll 16
        for (int ccp = 0; ccp < 64; ccp++) {
            uint32_t u = vv[ccp];
            p = fmaf(__uint_as_float(u << 16),         sW[(2 * ccp) * 32 + j],     p);
            p = fmaf(__uint_as_float(u & 0xffff0000u), sW[(2 * ccp + 1) * 32 + j], p);
        }
        float a = p > 0.f ? p : expm1f(p);
        out[n * 32 + j] = hin[n * 32 + j] + a;
    }
}

extern "C" void kernel_launch(void* const* d_in, const int* in_sizes, int n_in,
                              void* d_out, int out_size, void* d_ws, size_t ws_size,
                              hipStream_t stream) {
    const float* hin      = (const float*)d_in[0];
    const int*   src      = (const int*)d_in[1];
    const int*   dst      = (const int*)d_in[2];
    const float* Wfc      = (const float*)d_in[3];
    const float* attn_l   = (const float*)d_in[4];
    const float* attn_r   = (const float*)d_in[5];
    const float* bias_gat = (const float*)d_in[6];
    const float* Wout     = (const float*)d_in[7];
    const float* b_out    = (const float*)d_in[8];
    float* out = (float*)d_out;

    char* ws = (char*)d_ws;
    size_t o = 0;
    uint32_t* feat = (uint32_t*)(ws + o); o += (size_t)NNODE * 64 * 4;  // bf16 x128
    uint32_t* svb  = (uint32_t*)(ws + o); o += (size_t)NNODE * 64 * 4;  // bf16 x128
    float* el      = (float*)(ws + o);    o += (size_t)NNODE * 4 * 4;
    float* er      = (float*)(ws + o);    o += (size_t)NNODE * 4 * 4;
    int*   cnt     = (int*)(ws + o);      o += (size_t)4 * NNODE * 4;   // 4 sub-histograms
    unsigned* word = (unsigned*)(ws + o); o += (size_t)NBLK_SCAN * 4;   // contiguous w/ cnt
    int*   offa    = (int*)(ws + o);      o += (size_t)(NNODE + 1) * 4;
    int*   pb      = (int*)(ws + o);      o += (size_t)4 * NNODE * 4;   // per-part bases
    int*   pos     = (int*)(ws + o);      o += (size_t)NEDGE * 4;
    int*   ssrc    = (int*)(ws + o);      o += (size_t)NEDGE * 4;

    // zero cnt4 + scan words each launch (flags must reset for determinism)
    hipMemsetAsync(cnt, 0, (size_t)(4 * NNODE + NBLK_SCAN) * 4, stream);

    k_proj_hist<<<KPH_BLOCKS, 256, 0, stream>>>(
        hin, Wfc, attn_l, attn_r, feat, el, er, dst, cnt, pos);
    k_scan<<<NBLK_SCAN, 256, 0, stream>>>(cnt, word, offa, pb);
    k_scatter<<<(NEDGE / 4 + 255) / 256, 256, 0, stream>>>(src, dst, pos, pb, ssrc);
    k_gather<<<NNODE / NPB, 256, 0, stream>>>(offa, ssrc, el, er, feat, bias_gat, svb);
    k_out<<<NNODE / ONPB, 256, 0, stream>>>(svb, Wout, b_out, hin, out);
}

// Round 13
// 221.114 us; speedup vs baseline: 1.0673x; 1.0673x over previous
//
#include <hip/hip_runtime.h>
#include <hip/hip_bf16.h>

#define NNODE 100000
#define NEDGE 1600000
#define NBLK_SCAN 98     // ceil(100000/1024)
#define KPH_BLOCKS 1564  // covers 100096 nodes (64/block) and 400384 int4 edges
#define QINT4 100000     // int4s per histogram part (4 parts x 400k edges)
#define FLAGBIT 0x80000000u

static __device__ __forceinline__ uint32_t pack_bf16(float a, float b) {
    __hip_bfloat162 t = __float22bfloat162_rn(make_float2(a, b));
    return *(uint32_t*)&t;
}

// ---------------- K1: 4-way split hist atomics + register-only proj, fused ----------------
__global__ __launch_bounds__(256) void k_proj_hist(
        const float* __restrict__ hin, const float* __restrict__ Wfc,
        const float* __restrict__ attn_l, const float* __restrict__ attn_r,
        uint32_t* __restrict__ feat, float* __restrict__ el, float* __restrict__ er,
        const int* __restrict__ dst, int* __restrict__ cnt, int* __restrict__ pos) {
    int tid = threadIdx.x;
    // ---- hist: one int4 per thread, atomics to this quarter's sub-histogram ----
    int ei = blockIdx.x * 256 + tid;
    bool have = ei < NEDGE / 4;
    int4 d, p;
    int* cntp = nullptr;
    if (have) {
        unsigned part = (unsigned)ei / (unsigned)QINT4;   // 0..3
        cntp = cnt + part * NNODE;
        d = ((const int4*)dst)[ei];
        p.x = atomicAdd(&cntp[d.x], 1);
        p.y = atomicAdd(&cntp[d.y], 1);
        p.z = atomicAdd(&cntp[d.z], 1);
        p.w = atomicAdd(&cntp[d.w], 1);
    }
    // ---- proj: 16 nodes per wave, lane owns 2 cols, W pair in regs ----
    int l = tid & 63;
    int w = tid >> 6;
    int nbase = blockIdx.x * 64 + w * 16;
    int c0 = l * 2;
    float2 wreg[32];
#pragma unroll
    for (int k = 0; k < 32; k++)
        wreg[k] = *(const float2*)&Wfc[k * 128 + c0];
    float al0 = attn_l[c0], al1 = attn_l[c0 + 1];
    float ar0 = attn_r[c0], ar1 = attn_r[c0 + 1];
#pragma unroll 4
    for (int i = 0; i < 16; i++) {
        int n = nbase + i;
        if (n >= NNODE) break;           // wave-uniform
        float4 hv[8];
#pragma unroll
        for (int j = 0; j < 8; j++)
            hv[j] = *(const float4*)&hin[n * 32 + j * 4];   // broadcast load
        float a0 = 0.f, a1 = 0.f;
#pragma unroll
        for (int j = 0; j < 8; j++) {
            a0 = fmaf(hv[j].x, wreg[j * 4 + 0].x, a0); a1 = fmaf(hv[j].x, wreg[j * 4 + 0].y, a1);
            a0 = fmaf(hv[j].y, wreg[j * 4 + 1].x, a0); a1 = fmaf(hv[j].y, wreg[j * 4 + 1].y, a1);
            a0 = fmaf(hv[j].z, wreg[j * 4 + 2].x, a0); a1 = fmaf(hv[j].z, wreg[j * 4 + 2].y, a1);
            a0 = fmaf(hv[j].w, wreg[j * 4 + 3].x, a0); a1 = fmaf(hv[j].w, wreg[j * 4 + 3].y, a1);
        }
        float ep = a0 * al0 + a1 * al1;
        float rp = a0 * ar0 + a1 * ar1;
#pragma unroll
        for (int m = 8; m; m >>= 1) {
            ep += __shfl_xor(ep, m);
            rp += __shfl_xor(rp, m);
        }
        if ((l & 15) == 0) {
            el[n * 4 + (l >> 4)] = ep;
            er[n * 4 + (l >> 4)] = rp;
        }
        feat[(size_t)n * 64 + l] = pack_bf16(a0, a1);       // coalesced u32
    }
    // ---- pos (within-part rank) write: waits on atomic returns (hidden behind proj) ----
    if (have) ((int4*)pos)[ei] = p;
}

// ---------------- single-kernel scan: cnt4 -> offa + per-part bases pb[4][N] ----------------
__global__ __launch_bounds__(256) void k_scan(
        const int* __restrict__ cnt, unsigned* __restrict__ word,
        int* __restrict__ offa, int* __restrict__ pb) {
    __shared__ int s[256];
    __shared__ int sBase;
    int t = threadIdx.x;
    int b = blockIdx.x;
    int base = b * 1024 + t * 4;
    int vA[4], vB[4], vC[4], v[4];
#pragma unroll
    for (int i = 0; i < 4; i++) {
        int n = base + i;
        if (n < NNODE) {
            int a = cnt[n], bb = cnt[NNODE + n], c = cnt[2 * NNODE + n], dd = cnt[3 * NNODE + n];
            vA[i] = a; vB[i] = bb; vC[i] = c;
            v[i] = a + bb + c + dd;
        } else { vA[i] = vB[i] = vC[i] = 0; v[i] = 0; }
    }
    int sum = v[0] + v[1] + v[2] + v[3];
    s[t] = sum;
    __syncthreads();
    for (int d = 1; d < 256; d <<= 1) {
        int x = (t >= d) ? s[t - d] : 0;
        __syncthreads();
        s[t] += x;
        __syncthreads();
    }
    int excl = s[t] - sum;
    if (t == 255)
        __hip_atomic_store(&word[b], (unsigned)s[255] | FLAGBIT,
                           __ATOMIC_RELEASE, __HIP_MEMORY_SCOPE_AGENT);
    if (t < 64) {
        unsigned acc = 0;
        for (int i = t; i < b; i += 64) {
            unsigned wv;
            do {
                wv = __hip_atomic_load(&word[i], __ATOMIC_ACQUIRE, __HIP_MEMORY_SCOPE_AGENT);
            } while (!(wv & FLAGBIT));
            acc += wv & ~FLAGBIT;
        }
#pragma unroll
        for (int o = 32; o; o >>= 1) acc += __shfl_down(acc, o);
        if (t == 0) sBase = (int)acc;
    }
    __syncthreads();
    int o0 = sBase + excl;
#pragma unroll
    for (int i = 0; i < 4; i++) {
        int n = base + i;
        if (n < NNODE) {
            offa[n] = o0;
            pb[n] = o0;
            pb[NNODE + n] = o0 + vA[i];
            pb[2 * NNODE + n] = o0 + vA[i] + vB[i];
            pb[3 * NNODE + n] = o0 + vA[i] + vB[i] + vC[i];
            o0 += v[i];
        }
    }
    if (b == NBLK_SCAN - 1 && t == 255) offa[NNODE] = NEDGE;
}

// ---------------- scatter: atomic-free, part-base + within-part rank ----------------
__global__ __launch_bounds__(256) void k_scatter(const int* __restrict__ src,
                                                 const int* __restrict__ dst,
                                                 const int* __restrict__ pos,
                                                 const int* __restrict__ pb,
                                                 int* __restrict__ ssrc) {
    int i = blockIdx.x * 256 + threadIdx.x;
    if (i >= NEDGE / 4) return;
    unsigned part = (unsigned)i / (unsigned)QINT4;
    const int* pbp = pb + part * NNODE;
    int4 s = ((const int4*)src)[i];
    int4 d = ((const int4*)dst)[i];
    int4 p = ((const int4*)pos)[i];
    int o0 = pbp[d.x];
    int o1 = pbp[d.y];
    int o2 = pbp[d.z];
    int o3 = pbp[d.w];
    ssrc[o0 + p.x] = s.x;
    ssrc[o1 + p.y] = s.y;
    ssrc[o2 + p.z] = s.z;
    ssrc[o3 + p.w] = s.w;
}

// ---------------- K2': wave-per-node gather + fused epilogue, uint2 metadata ----
#define NPB 4
__global__ __launch_bounds__(256) void k_gather(
        const int* __restrict__ off, const int* __restrict__ ssrc,
        const float* __restrict__ el, const float* __restrict__ er,
        const uint32_t* __restrict__ feat, const float* __restrict__ bias_gat,
        const float* __restrict__ Wout, const float* __restrict__ b_out,
        const float* __restrict__ hin, float* __restrict__ out) {
    __shared__ uint32_t sWu[2048];                    // 8 KB bf16-packed Wout pairs
    __shared__ __align__(8) uint2 sSE[NPB][4][64];    // 8 KB {feat dword off, exp bits}
    __shared__ float sv[NPB][128];                    // 2 KB
    int tid = threadIdx.x;
    for (int i = tid; i < 2048; i += 256) {
        int ccp = i >> 5, jj = i & 31;
        sWu[i] = pack_bf16(Wout[(2 * ccp) * 32 + jj], Wout[(2 * ccp + 1) * 32 + jj]);
    }
    __syncthreads();   // sWu visible to all waves; everything below is wave-local
    int w = tid >> 6;
    int l = tid & 63;
    int n = blockIdx.x * NPB + w;   // grid exact: 25000*4 = 100000
    int c0 = l * 2;
    int hh = l >> 4;
    float2 acc = make_float2(0.f, 0.f);
    float den = 0.f;
    int beg = off[n], end = off[n + 1];
    float4 erv = *(const float4*)&er[n * 4];

    for (int base = beg; base < end; base += 64) {
        int cnt = end - base; if (cnt > 64) cnt = 64;
        // phase A: edge metadata load + all-head exp(); pad slots: lane0's row, weight 0
        int s = 0;
        float4 e4 = make_float4(0.f, 0.f, 0.f, 0.f);
        if (l < cnt) {
            s = ssrc[base + l];
            float4 ev = *(const float4*)&el[s * 4];
            e4.x = ev.x + erv.x; e4.x = e4.x > 0.f ? e4.x : 0.2f * e4.x; e4.x = __expf(e4.x);
            e4.y = ev.y + erv.y; e4.y = e4.y > 0.f ? e4.y : 0.2f * e4.y; e4.y = __expf(e4.y);
            e4.z = ev.z + erv.z; e4.z = e4.z > 0.f ? e4.z : 0.2f * e4.z; e4.z = __expf(e4.z);
            e4.w = ev.w + erv.w; e4.w = e4.w > 0.f ? e4.w : 0.2f * e4.w; e4.w = __expf(e4.w);
        }
        int s0 = __shfl(s, 0);
        if (l >= cnt) s = s0;
        uint32_t dwoff = (uint32_t)s * 64u;
        sSE[w][0][l] = make_uint2(dwoff, __float_as_uint(e4.x));
        sSE[w][1][l] = make_uint2(dwoff, __float_as_uint(e4.y));
        sSE[w][2][l] = make_uint2(dwoff, __float_as_uint(e4.z));
        sSE[w][3][l] = make_uint2(dwoff, __float_as_uint(e4.w));
        __builtin_amdgcn_wave_barrier();
        // phase B: one ds_read_b64 per edge; 8 feat rows in flight
        int rounds = (cnt + 7) >> 3;
        for (int r = 0; r < rounds; r++) {
            int e = r * 8;
            uint2 m[8]; uint32_t uu[8];
#pragma unroll
            for (int q = 0; q < 8; q++)
                m[q] = sSE[w][hh][e + q];      // broadcast within 16-lane head group
#pragma unroll
            for (int q = 0; q < 8; q++)
                uu[q] = feat[m[q].x + (uint32_t)l];
#pragma unroll
            for (int q = 0; q < 8; q++) {
                float x = __uint_as_float(m[q].y);
                den += x;
                acc.x = fmaf(x, __uint_as_float(uu[q] << 16), acc.x);
                acc.y = fmaf(x, __uint_as_float(uu[q] & 0xffff0000u), acc.y);
            }
        }
        __builtin_amdgcn_wave_barrier();
    }
    float inv = 1.f / fmaxf(den, 1e-9f);
    float2 val;
    val.x = acc.x * inv + bias_gat[c0];
    val.y = acc.y * inv + bias_gat[c0 + 1];
    *(float2*)&sv[w][c0] = val;
    __builtin_amdgcn_wave_barrier();
    // epilogue (wave-local): out = h + ELU(sv @ Wout + b_out)
    int j = l & 31, g2 = l >> 5;
    float p = 0.f;
    const float* vv = sv[w];
#pragma unroll 8
    for (int ccp = g2 * 32; ccp < g2 * 32 + 32; ccp++) {
        uint32_t u = sWu[ccp * 32 + j];
        p = fmaf(vv[2 * ccp],     __uint_as_float(u << 16),          p);
        p = fmaf(vv[2 * ccp + 1], __uint_as_float(u & 0xffff0000u), p);
    }
    p += __shfl_xor(p, 32);
    if (g2 == 0) {
        float a = p > 0.f ? p : expm1f(p);
        out[n * 32 + j] = hin[n * 32 + j] + a;
    }
}

extern "C" void kernel_launch(void* const* d_in, const int* in_sizes, int n_in,
                              void* d_out, int out_size, void* d_ws, size_t ws_size,
                              hipStream_t stream) {
    const float* hin      = (const float*)d_in[0];
    const int*   src      = (const int*)d_in[1];
    const int*   dst      = (const int*)d_in[2];
    const float* Wfc      = (const float*)d_in[3];
    const float* attn_l   = (const float*)d_in[4];
    const float* attn_r   = (const float*)d_in[5];
    const float* bias_gat = (const float*)d_in[6];
    const float* Wout     = (const float*)d_in[7];
    const float* b_out    = (const float*)d_in[8];
    float* out = (float*)d_out;

    char* ws = (char*)d_ws;
    size_t o = 0;
    uint32_t* feat = (uint32_t*)(ws + o); o += (size_t)NNODE * 64 * 4;  // bf16 x128
    float* el      = (float*)(ws + o);    o += (size_t)NNODE * 4 * 4;
    float* er      = (float*)(ws + o);    o += (size_t)NNODE * 4 * 4;
    int*   cnt     = (int*)(ws + o);      o += (size_t)4 * NNODE * 4;   // 4 sub-histograms
    unsigned* word = (unsigned*)(ws + o); o += (size_t)NBLK_SCAN * 4;   // contiguous w/ cnt
    int*   offa    = (int*)(ws + o);      o += (size_t)(NNODE + 1) * 4;
    int*   pb      = (int*)(ws + o);      o += (size_t)4 * NNODE * 4;   // per-part bases
    int*   pos     = (int*)(ws + o);      o += (size_t)NEDGE * 4;
    int*   ssrc    = (int*)(ws + o);      o += (size_t)NEDGE * 4;

    // zero cnt4 + scan words each launch (flags must reset for determinism)
    hipMemsetAsync(cnt, 0, (size_t)(4 * NNODE + NBLK_SCAN) * 4, stream);

    k_proj_hist<<<KPH_BLOCKS, 256, 0, stream>>>(
        hin, Wfc, attn_l, attn_r, feat, el, er, dst, cnt, pos);
    k_scan<<<NBLK_SCAN, 256, 0, stream>>>(cnt, word, offa, pb);
    k_scatter<<<(NEDGE / 4 + 255) / 256, 256, 0, stream>>>(src, dst, pos, pb, ssrc);
    k_gather<<<NNODE / NPB, 256, 0, stream>>>(offa, ssrc, el, er, feat, bias_gat,
                                              Wout, b_out, hin, out);
}

// Round 14
// 218.860 us; speedup vs baseline: 1.0783x; 1.0103x over previous
//
#include <hip/hip_runtime.h>
#include <hip/hip_bf16.h>

#define NNODE 100000
#define NEDGE 1600000
#define NBLK_SCAN 98     // ceil(100000/1024)
#define KPH_BLOCKS 1564  // covers 100096 nodes (64/block) and 400384 int4 edges
#define QINT4 100000     // int4s per histogram part (4 parts x 400k edges)
#define FLAGBIT 0x80000000u

#if __has_builtin(__builtin_amdgcn_cvt_pk_fp8_f32) && __has_builtin(__builtin_amdgcn_cvt_pk_f32_fp8)
#define HAVE_FP8CVT 1
typedef float floatx2 __attribute__((ext_vector_type(2)));
#endif

#ifndef HAVE_FP8CVT
static __device__ __forceinline__ uint32_t fp8_enc1(float x) {
    uint32_t b = __float_as_uint(x);
    uint32_t s = (b >> 24) & 0x80u;
    float ax = fabsf(x);
    if (ax >= 448.f) return s | 0x7Eu;
    if (ax < 0.015625f) {                       // subnormal range, quantum 2^-9
        uint32_t m = (uint32_t)__float2int_rn(ax * 512.f);
        if (m > 7u) return s | (1u << 3);
        return s | m;
    }
    uint32_t mag = b & 0x7fffffffu;
    mag += 0x7ffffu + ((mag >> 20) & 1u);       // RNE on 20 dropped bits
    int e8 = (int)(mag >> 23) - 120;
    if (e8 > 15) return s | 0x7Eu;
    return s | ((uint32_t)e8 << 3) | ((mag >> 20) & 7u);
}
static __device__ __forceinline__ float fp8_dec1(uint32_t v) {
    uint32_t s = (v & 0x80u) << 24;
    uint32_t e = (v >> 3) & 0xFu, m = v & 7u;
    uint32_t bits;
    if (e) bits = s | ((e + 120u) << 23) | (m << 20);
    else bits = m ? (s | (__float_as_uint((float)m) - (9u << 23))) : s;
    return __uint_as_float(bits);
}
#endif

static __device__ __forceinline__ unsigned short enc_fp8x2(float a, float b) {
#ifdef HAVE_FP8CVT
    return (unsigned short)(__builtin_amdgcn_cvt_pk_fp8_f32(a, b, 0, false) & 0xffff);
#else
    return (unsigned short)(fp8_enc1(a) | (fp8_enc1(b) << 8));
#endif
}
static __device__ __forceinline__ float2 dec_fp8x2(uint32_t u) {
#ifdef HAVE_FP8CVT
    floatx2 v = __builtin_amdgcn_cvt_pk_f32_fp8((int)u, false);
    return make_float2(v.x, v.y);
#else
    return make_float2(fp8_dec1(u & 0xffu), fp8_dec1((u >> 8) & 0xffu));
#endif
}

static __device__ __forceinline__ uint32_t pack_bf16(float a, float b) {
    __hip_bfloat162 t = __float22bfloat162_rn(make_float2(a, b));
    return *(uint32_t*)&t;
}

// ---------------- K1: 4-way split hist atomics + register-only proj, fused ----------------
__global__ __launch_bounds__(256) void k_proj_hist(
        const float* __restrict__ hin, const float* __restrict__ Wfc,
        const float* __restrict__ attn_l, const float* __restrict__ attn_r,
        unsigned short* __restrict__ fe8, float* __restrict__ el, float* __restrict__ er,
        const int* __restrict__ dst, int* __restrict__ cnt, int* __restrict__ pos) {
    int tid = threadIdx.x;
    // ---- hist: one int4 per thread, atomics to this quarter's sub-histogram ----
    int ei = blockIdx.x * 256 + tid;
    bool have = ei < NEDGE / 4;
    int4 d, p;
    int* cntp = nullptr;
    if (have) {
        unsigned part = (unsigned)ei / (unsigned)QINT4;   // 0..3
        cntp = cnt + part * NNODE;
        d = ((const int4*)dst)[ei];
        p.x = atomicAdd(&cntp[d.x], 1);
        p.y = atomicAdd(&cntp[d.y], 1);
        p.z = atomicAdd(&cntp[d.z], 1);
        p.w = atomicAdd(&cntp[d.w], 1);
    }
    // ---- proj: 16 nodes per wave, lane owns 2 cols, W pair in regs ----
    int l = tid & 63;
    int w = tid >> 6;
    int nbase = blockIdx.x * 64 + w * 16;
    int c0 = l * 2;
    float2 wreg[32];
#pragma unroll
    for (int k = 0; k < 32; k++)
        wreg[k] = *(const float2*)&Wfc[k * 128 + c0];
    float al0 = attn_l[c0], al1 = attn_l[c0 + 1];
    float ar0 = attn_r[c0], ar1 = attn_r[c0 + 1];
#pragma unroll 4
    for (int i = 0; i < 16; i++) {
        int n = nbase + i;
        if (n >= NNODE) break;           // wave-uniform
        float4 hv[8];
#pragma unroll
        for (int j = 0; j < 8; j++)
            hv[j] = *(const float4*)&hin[n * 32 + j * 4];   // broadcast load
        float a0 = 0.f, a1 = 0.f;
#pragma unroll
        for (int j = 0; j < 8; j++) {
            a0 = fmaf(hv[j].x, wreg[j * 4 + 0].x, a0); a1 = fmaf(hv[j].x, wreg[j * 4 + 0].y, a1);
            a0 = fmaf(hv[j].y, wreg[j * 4 + 1].x, a0); a1 = fmaf(hv[j].y, wreg[j * 4 + 1].y, a1);
            a0 = fmaf(hv[j].z, wreg[j * 4 + 2].x, a0); a1 = fmaf(hv[j].z, wreg[j * 4 + 2].y, a1);
            a0 = fmaf(hv[j].w, wreg[j * 4 + 3].x, a0); a1 = fmaf(hv[j].w, wreg[j * 4 + 3].y, a1);
        }
        float ep = a0 * al0 + a1 * al1;
        float rp = a0 * ar0 + a1 * ar1;
#pragma unroll
        for (int m = 8; m; m >>= 1) {
            ep += __shfl_xor(ep, m);
            rp += __shfl_xor(rp, m);
        }
        if ((l & 15) == 0) {
            el[n * 4 + (l >> 4)] = ep;
            er[n * 4 + (l >> 4)] = rp;
        }
        fe8[(size_t)n * 64 + l] = enc_fp8x2(a0, a1);        // coalesced ushort
    }
    // ---- pos (within-part rank) write: waits on atomic returns (hidden behind proj) ----
    if (have) ((int4*)pos)[ei] = p;
}

// ---------------- single-kernel scan: cnt4 -> offa + per-part bases pb[4][N] ----------------
__global__ __launch_bounds__(256) void k_scan(
        const int* __restrict__ cnt, unsigned* __restrict__ word,
        int* __restrict__ offa, int* __restrict__ pb) {
    __shared__ int s[256];
    __shared__ int sBase;
    int t = threadIdx.x;
    int b = blockIdx.x;
    int base = b * 1024 + t * 4;
    int vA[4], vB[4], vC[4], v[4];
#pragma unroll
    for (int i = 0; i < 4; i++) {
        int n = base + i;
        if (n < NNODE) {
            int a = cnt[n], bb = cnt[NNODE + n], c = cnt[2 * NNODE + n], dd = cnt[3 * NNODE + n];
            vA[i] = a; vB[i] = bb; vC[i] = c;
            v[i] = a + bb + c + dd;
        } else { vA[i] = vB[i] = vC[i] = 0; v[i] = 0; }
    }
    int sum = v[0] + v[1] + v[2] + v[3];
    s[t] = sum;
    __syncthreads();
    for (int d = 1; d < 256; d <<= 1) {
        int x = (t >= d) ? s[t - d] : 0;
        __syncthreads();
        s[t] += x;
        __syncthreads();
    }
    int excl = s[t] - sum;
    if (t == 255)
        __hip_atomic_store(&word[b], (unsigned)s[255] | FLAGBIT,
                           __ATOMIC_RELEASE, __HIP_MEMORY_SCOPE_AGENT);
    if (t < 64) {
        unsigned acc = 0;
        for (int i = t; i < b; i += 64) {
            unsigned wv;
            do {
                wv = __hip_atomic_load(&word[i], __ATOMIC_ACQUIRE, __HIP_MEMORY_SCOPE_AGENT);
            } while (!(wv & FLAGBIT));
            acc += wv & ~FLAGBIT;
        }
#pragma unroll
        for (int o = 32; o; o >>= 1) acc += __shfl_down(acc, o);
        if (t == 0) sBase = (int)acc;
    }
    __syncthreads();
    int o0 = sBase + excl;
#pragma unroll
    for (int i = 0; i < 4; i++) {
        int n = base + i;
        if (n < NNODE) {
            offa[n] = o0;
            pb[n] = o0;
            pb[NNODE + n] = o0 + vA[i];
            pb[2 * NNODE + n] = o0 + vA[i] + vB[i];
            pb[3 * NNODE + n] = o0 + vA[i] + vB[i] + vC[i];
            o0 += v[i];
        }
    }
    if (b == NBLK_SCAN - 1 && t == 255) offa[NNODE] = NEDGE;
}

// ---------------- scatter: atomic-free, part-base + within-part rank ----------------
__global__ __launch_bounds__(256) void k_scatter(const int* __restrict__ src,
                                                 const int* __restrict__ dst,
                                                 const int* __restrict__ pos,
                                                 const int* __restrict__ pb,
                                                 int* __restrict__ ssrc) {
    int i = blockIdx.x * 256 + threadIdx.x;
    if (i >= NEDGE / 4) return;
    unsigned part = (unsigned)i / (unsigned)QINT4;
    const int* pbp = pb + part * NNODE;
    int4 s = ((const int4*)src)[i];
    int4 d = ((const int4*)dst)[i];
    int4 p = ((const int4*)pos)[i];
    int o0 = pbp[d.x];
    int o1 = pbp[d.y];
    int o2 = pbp[d.z];
    int o3 = pbp[d.w];
    ssrc[o0 + p.x] = s.x;
    ssrc[o1 + p.y] = s.y;
    ssrc[o2 + p.z] = s.z;
    ssrc[o3 + p.w] = s.w;
}

// ---------------- K2': wave-per-node gather + fused epilogue, fp8 feat ----
#define NPB 4
__global__ __launch_bounds__(256) void k_gather(
        const int* __restrict__ off, const int* __restrict__ ssrc,
        const float* __restrict__ el, const float* __restrict__ er,
        const unsigned short* __restrict__ fe8, const float* __restrict__ bias_gat,
        const float* __restrict__ Wout, const float* __restrict__ b_out,
        const float* __restrict__ hin, float* __restrict__ out) {
    __shared__ uint32_t sWu[2048];                    // 8 KB bf16-packed Wout pairs
    __shared__ __align__(8) uint2 sSE[NPB][4][64];    // 8 KB {feat ushort off, exp bits}
    __shared__ float sv[NPB][128];                    // 2 KB
    int tid = threadIdx.x;
    for (int i = tid; i < 2048; i += 256) {
        int ccp = i >> 5, jj = i & 31;
        sWu[i] = pack_bf16(Wout[(2 * ccp) * 32 + jj], Wout[(2 * ccp + 1) * 32 + jj]);
    }
    __syncthreads();   // sWu visible to all waves; everything below is wave-local
    int w = tid >> 6;
    int l = tid & 63;
    int n = blockIdx.x * NPB + w;   // grid exact: 25000*4 = 100000
    int c0 = l * 2;
    int hh = l >> 4;
    float2 acc = make_float2(0.f, 0.f);
    float den = 0.f;
    int beg = off[n], end = off[n + 1];
    float4 erv = *(const float4*)&er[n * 4];

    for (int base = beg; base < end; base += 64) {
        int cnt = end - base; if (cnt > 64) cnt = 64;
        // phase A: edge metadata load + all-head exp(); pad slots: lane0's row, weight 0
        int s = 0;
        float4 e4 = make_float4(0.f, 0.f, 0.f, 0.f);
        if (l < cnt) {
            s = ssrc[base + l];
            float4 ev = *(const float4*)&el[s * 4];
            e4.x = ev.x + erv.x; e4.x = e4.x > 0.f ? e4.x : 0.2f * e4.x; e4.x = __expf(e4.x);
            e4.y = ev.y + erv.y; e4.y = e4.y > 0.f ? e4.y : 0.2f * e4.y; e4.y = __expf(e4.y);
            e4.z = ev.z + erv.z; e4.z = e4.z > 0.f ? e4.z : 0.2f * e4.z; e4.z = __expf(e4.z);
            e4.w = ev.w + erv.w; e4.w = e4.w > 0.f ? e4.w : 0.2f * e4.w; e4.w = __expf(e4.w);
        }
        int s0 = __shfl(s, 0);
        if (l >= cnt) s = s0;
        uint32_t uoff = (uint32_t)s * 64u;            // ushort index of row base
        sSE[w][0][l] = make_uint2(uoff, __float_as_uint(e4.x));
        sSE[w][1][l] = make_uint2(uoff, __float_as_uint(e4.y));
        sSE[w][2][l] = make_uint2(uoff, __float_as_uint(e4.z));
        sSE[w][3][l] = make_uint2(uoff, __float_as_uint(e4.w));
        __builtin_amdgcn_wave_barrier();
        // phase B: one ds_read_b64 + one ushort load per edge; 8 rows in flight
        int rounds = (cnt + 7) >> 3;
        for (int r = 0; r < rounds; r++) {
            int e = r * 8;
            uint2 m[8]; uint32_t uu[8];
#pragma unroll
            for (int q = 0; q < 8; q++)
                m[q] = sSE[w][hh][e + q];      // broadcast within 16-lane head group
#pragma unroll
            for (int q = 0; q < 8; q++)
                uu[q] = fe8[m[q].x + (uint32_t)l];
#pragma unroll
            for (int q = 0; q < 8; q++) {
                float x = __uint_as_float(m[q].y);
                float2 f = dec_fp8x2(uu[q]);
                den += x;
                acc.x = fmaf(x, f.x, acc.x);
                acc.y = fmaf(x, f.y, acc.y);
            }
        }
        __builtin_amdgcn_wave_barrier();
    }
    float inv = 1.f / fmaxf(den, 1e-9f);
    float2 val;
    val.x = acc.x * inv + bias_gat[c0];
    val.y = acc.y * inv + bias_gat[c0 + 1];
    *(float2*)&sv[w][c0] = val;
    __builtin_amdgcn_wave_barrier();
    // epilogue (wave-local): out = h + ELU(sv @ Wout + b_out)
    int j = l & 31, g2 = l >> 5;
    float p = 0.f;
    const float* vv = sv[w];
#pragma unroll 8
    for (int ccp = g2 * 32; ccp < g2 * 32 + 32; ccp++) {
        uint32_t u = sWu[ccp * 32 + j];
        p = fmaf(vv[2 * ccp],     __uint_as_float(u << 16),          p);
        p = fmaf(vv[2 * ccp + 1], __uint_as_float(u & 0xffff0000u), p);
    }
    p += __shfl_xor(p, 32);
    if (g2 == 0) {
        float a = p > 0.f ? p : expm1f(p);
        out[n * 32 + j] = hin[n * 32 + j] + a;
    }
}

extern "C" void kernel_launch(void* const* d_in, const int* in_sizes, int n_in,
                              void* d_out, int out_size, void* d_ws, size_t ws_size,
                              hipStream_t stream) {
    const float* hin      = (const float*)d_in[0];
    const int*   src      = (const int*)d_in[1];
    const int*   dst      = (const int*)d_in[2];
    const float* Wfc      = (const float*)d_in[3];
    const float* attn_l   = (const float*)d_in[4];
    const float* attn_r   = (const float*)d_in[5];
    const float* bias_gat = (const float*)d_in[6];
    const float* Wout     = (const float*)d_in[7];
    const float* b_out    = (const float*)d_in[8];
    float* out = (float*)d_out;

    char* ws = (char*)d_ws;
    size_t o = 0;
    unsigned short* fe8 = (unsigned short*)(ws + o); o += (size_t)NNODE * 64 * 2;  // fp8 x128
    o = (o + 15) & ~(size_t)15;
    float* el      = (float*)(ws + o);    o += (size_t)NNODE * 4 * 4;
    float* er      = (float*)(ws + o);    o += (size_t)NNODE * 4 * 4;
    int*   cnt     = (int*)(ws + o);      o += (size_t)4 * NNODE * 4;   // 4 sub-histograms
    unsigned* word = (unsigned*)(ws + o); o += (size_t)NBLK_SCAN * 4;   // contiguous w/ cnt
    int*   offa    = (int*)(ws + o);      o += (size_t)(NNODE + 1) * 4;
    int*   pb      = (int*)(ws + o);      o += (size_t)4 * NNODE * 4;   // per-part bases
    int*   pos     = (int*)(ws + o);      o += (size_t)NEDGE * 4;
    int*   ssrc    = (int*)(ws + o);      o += (size_t)NEDGE * 4;

    // zero cnt4 + scan words each launch (flags must reset for determinism)
    hipMemsetAsync(cnt, 0, (size_t)(4 * NNODE + NBLK_SCAN) * 4, stream);

    k_proj_hist<<<KPH_BLOCKS, 256, 0, stream>>>(
        hin, Wfc, attn_l, attn_r, fe8, el, er, dst, cnt, pos);
    k_scan<<<NBLK_SCAN, 256, 0, stream>>>(cnt, word, offa, pb);
    k_scatter<<<(NEDGE / 4 + 255) / 256, 256, 0, stream>>>(src, dst, pos, pb, ssrc);
    k_gather<<<NNODE / NPB, 256, 0, stream>>>(offa, ssrc, el, er, fe8, bias_gat,
                                              Wout, b_out, hin, out);
}